// Round 1
// baseline (1582.984 us; speedup 1.0000x reference)
//
#include <hip/hip_runtime.h>
#include <hip/hip_bf16.h>
#include <cstddef>

// Problem constants (from reference setup_inputs)
#define NB     16
#define CIN    128
#define COUT   128
#define HH     128
#define WWID   128
#define TILE   32
#define THR    1e-6f

// Conv block tile
#define CI_BLK 16
#define CO_BLK 32
#define H_BLK  8
#define W_BLK  32

// ---------------------------------------------------------------------------
// Kernel 1: per-tile activity flags.  flags[n*16 + th*4 + tw] = 1.0 if any
// |x| > THR within the 32x32 spatial tile across all 128 channels.
// Early-exit: dense-random tiles exit after the first chunk (~4KB read).
// ---------------------------------------------------------------------------
__global__ __launch_bounds__(256) void flags_kernel(const float* __restrict__ x,
                                                    float* __restrict__ flags) {
    const int b  = blockIdx.x;          // 0..255 : n*16 + tile
    const int n  = b >> 4;
    const int t  = b & 15;
    const int th = t >> 2;
    const int tw = t & 3;
    const float* base = x + ((size_t)n * CIN * HH * WWID) + (size_t)th * TILE * WWID + tw * TILE;

    __shared__ int found;
    if (threadIdx.x == 0) found = 0;
    __syncthreads();

    int done = 0;
    // 128 ch * 32 rows * 8 float4 = 32768 float4 chunks; 256 threads/iter
    for (int it = 0; it < 128 && !done; ++it) {
        const int m  = it * 256 + threadIdx.x;
        const int c  = m >> 8;          // channel
        const int r  = (m >> 3) & 31;   // row in tile
        const int cw = m & 7;           // float4 within row
        const float4 v = *(const float4*)(base + (size_t)c * (HH * WWID) + r * WWID + cw * 4);
        if (fabsf(v.x) > THR || fabsf(v.y) > THR || fabsf(v.z) > THR || fabsf(v.w) > THR)
            found = 1;                  // benign race (monotonic 0->1)
        __syncthreads();                // (A) all writes for iter visible
        done = found;                   // uniform read (no writes between A and B)
        __syncthreads();                // (B) all reads done before next iter's writes
    }
    if (threadIdx.x == 0) flags[b] = done ? 1.0f : 0.0f;
}

// ---------------------------------------------------------------------------
// Kernel 2: weight re-layout [CO][CI][3][3] -> w2[ci][k][co]  (one-off, 576KB)
// Makes conv-side staging: coalesced global reads + sequential LDS writes.
// ---------------------------------------------------------------------------
__global__ __launch_bounds__(256) void wtrans_kernel(const float* __restrict__ w,
                                                     float* __restrict__ w2) {
    const int f = blockIdx.x * 256 + threadIdx.x;   // f = (ci*9 + k)*128 + co
    if (f < CIN * 9 * COUT) {
        const int co = f & 127;
        const int rk = f >> 7;          // ci*9 + k
        const int ci = rk / 9;
        const int k  = rk - ci * 9;
        w2[f] = w[((size_t)co * CIN + ci) * 9 + k];
    }
}

// ---------------------------------------------------------------------------
// Kernel 3: direct 3x3 conv, pad 1, with per-tile input masking.
// Block tile: CO_BLK=32 x H_BLK=8 x W_BLK=32 outputs; C_in chunked by 16.
// Thread tile: 4 co x 2 h x 4 w = 32 accumulators.
// ---------------------------------------------------------------------------
struct SmemT {
    float s_in[CI_BLK][H_BLK + 2][W_BLK + 4];   // [16][10][36]  (36: pad, 144B rows)
    float s_w[CI_BLK][9][CO_BLK];               // [16][9][32]
    float s_flags[16];
};

#define ELT(v4, i) ((i) == 0 ? (v4).x : (i) == 1 ? (v4).y : (i) == 2 ? (v4).z : (v4).w)
#define GETIN(r, idx) ((idx) < 4 ? ELT(r4[r][0], (idx)) : ELT(r4[r][1], (idx) - 4))

__global__ __launch_bounds__(256, 3) void conv_kernel(const float* __restrict__ x,
                                                      const float* __restrict__ w2,
                                                      const float* __restrict__ bias,
                                                      const float* __restrict__ flags,
                                                      float* __restrict__ out) {
    __shared__ SmemT sm;
    const int tid  = threadIdx.x;
    const int wblk = blockIdx.x * W_BLK;
    const int hblk = blockIdx.y * H_BLK;
    const int z    = blockIdx.z;
    const int n    = z >> 2;
    const int cob  = (z & 3) * CO_BLK;

    if (tid < 16) sm.s_flags[tid] = flags[n * 16 + tid];

    const int wg   = tid & 7;          // w-group
    const int hg   = (tid >> 3) & 3;   // h-group
    const int cog  = tid >> 5;         // co-group
    const int w0   = wg * 4;
    const int h0   = hg * 2;
    const int co_t = cog * 4;

    float acc[4][2][4];
#pragma unroll
    for (int a = 0; a < 4; ++a)
#pragma unroll
        for (int b = 0; b < 2; ++b)
#pragma unroll
            for (int c = 0; c < 4; ++c) acc[a][b][c] = 0.0f;

    const size_t x_n = (size_t)n * CIN * HH * WWID;

    for (int cib = 0; cib < CIN; cib += CI_BLK) {
        __syncthreads();   // protect previous iteration's LDS reads

        // ---- stage input chunk [16][10][34] with halo, bounds + tile mask ----
        for (int f = tid; f < CI_BLK * 10 * 34; f += 256) {
            const int ci  = f / 340;
            const int rem = f - ci * 340;
            const int r   = rem / 34;
            const int c   = rem - r * 34;
            const int h_in = hblk + r - 1;
            const int w_in = wblk + c - 1;
            float v = 0.0f;
            if ((unsigned)h_in < (unsigned)HH && (unsigned)w_in < (unsigned)WWID) {
                v = x[x_n + (size_t)(cib + ci) * (HH * WWID) + (size_t)h_in * WWID + w_in]
                    * sm.s_flags[((h_in >> 5) << 2) + (w_in >> 5)];
            }
            sm.s_in[ci][r][c] = v;
        }
        // ---- stage weight chunk: w2[ci][k][cob..cob+31] -> s_w (sequential LDS) ----
        for (int f = tid; f < CI_BLK * 9 * CO_BLK; f += 256) {
            const int ci  = f / (9 * CO_BLK);
            const int rem = f - ci * (9 * CO_BLK);
            const int k   = rem / CO_BLK;
            const int co  = rem - k * CO_BLK;
            ((float*)sm.s_w)[f] = w2[(size_t)(cib + ci) * (9 * COUT) + k * COUT + cob + co];
        }
        __syncthreads();

        // ---- compute ----
#pragma unroll 2
        for (int ci = 0; ci < CI_BLK; ++ci) {
            float4 r4[4][2];
#pragma unroll
            for (int r = 0; r < 4; ++r) {
                r4[r][0] = *(const float4*)&sm.s_in[ci][h0 + r][w0];
                r4[r][1] = *(const float4*)&sm.s_in[ci][h0 + r][w0 + 4];
            }
#pragma unroll
            for (int kh = 0; kh < 3; ++kh) {
                const float4 wf0 = *(const float4*)&sm.s_w[ci][kh * 3 + 0][co_t];
                const float4 wf1 = *(const float4*)&sm.s_w[ci][kh * 3 + 1][co_t];
                const float4 wf2 = *(const float4*)&sm.s_w[ci][kh * 3 + 2][co_t];
#pragma unroll
                for (int hh = 0; hh < 2; ++hh) {
#pragma unroll
                    for (int ww = 0; ww < 4; ++ww) {
                        const float i0 = GETIN(hh + kh, ww + 0);
                        const float i1 = GETIN(hh + kh, ww + 1);
                        const float i2 = GETIN(hh + kh, ww + 2);
                        acc[0][hh][ww] = fmaf(i0, wf0.x, acc[0][hh][ww]);
                        acc[1][hh][ww] = fmaf(i0, wf0.y, acc[1][hh][ww]);
                        acc[2][hh][ww] = fmaf(i0, wf0.z, acc[2][hh][ww]);
                        acc[3][hh][ww] = fmaf(i0, wf0.w, acc[3][hh][ww]);
                        acc[0][hh][ww] = fmaf(i1, wf1.x, acc[0][hh][ww]);
                        acc[1][hh][ww] = fmaf(i1, wf1.y, acc[1][hh][ww]);
                        acc[2][hh][ww] = fmaf(i1, wf1.z, acc[2][hh][ww]);
                        acc[3][hh][ww] = fmaf(i1, wf1.w, acc[3][hh][ww]);
                        acc[0][hh][ww] = fmaf(i2, wf2.x, acc[0][hh][ww]);
                        acc[1][hh][ww] = fmaf(i2, wf2.y, acc[1][hh][ww]);
                        acc[2][hh][ww] = fmaf(i2, wf2.z, acc[2][hh][ww]);
                        acc[3][hh][ww] = fmaf(i2, wf2.w, acc[3][hh][ww]);
                    }
                }
            }
        }
    }

    // ---- epilogue: +bias, float4 stores ----
    const float4 b4 = *(const float4*)&bias[cob + co_t];
#pragma unroll
    for (int co = 0; co < 4; ++co) {
        const float bb = ELT(b4, co);
#pragma unroll
        for (int hh = 0; hh < 2; ++hh) {
            float4 o;
            o.x = acc[co][hh][0] + bb;
            o.y = acc[co][hh][1] + bb;
            o.z = acc[co][hh][2] + bb;
            o.w = acc[co][hh][3] + bb;
            const size_t off = ((size_t)(n * COUT + cob + co_t + co) * HH + (hblk + h0 + hh)) * WWID
                               + wblk + w0;
            *(float4*)&out[off] = o;
        }
    }
}

// ---------------------------------------------------------------------------
extern "C" void kernel_launch(void* const* d_in, const int* in_sizes, int n_in,
                              void* d_out, int out_size, void* d_ws, size_t ws_size,
                              hipStream_t stream) {
    const float* x    = (const float*)d_in[0];
    const float* w    = (const float*)d_in[1];
    const float* bias = (const float*)d_in[2];
    float* out = (float*)d_out;

    // workspace layout: [0,1024) flags (256 floats), [1024, +576KB) w2
    float* flags = (float*)d_ws;
    float* w2    = (float*)((char*)d_ws + 1024);

    flags_kernel<<<NB * 16, 256, 0, stream>>>(x, flags);
    wtrans_kernel<<<(CIN * 9 * COUT + 255) / 256, 256, 0, stream>>>(w, w2);

    dim3 grid(WWID / W_BLK, HH / H_BLK, NB * (COUT / CO_BLK));   // (4, 16, 64)
    conv_kernel<<<grid, 256, 0, stream>>>(x, w2, bias, flags, out);
}

// Round 2
// 1242.500 us; speedup vs baseline: 1.2740x; 1.2740x over previous
//
#include <hip/hip_runtime.h>
#include <hip/hip_bf16.h>
#include <cstddef>

// Problem constants (from reference setup_inputs)
#define NB     16
#define CIN    128
#define COUT   128
#define HH     128
#define WWID   128
#define TILE   32
#define THR    1e-6f

// Conv block tile
#define CI_BLK 8
#define CO_BLK 32
#define H_BLK  16
#define W_BLK  32
// Thread tile: 4 co x 4 h x 4 w = 64 outputs/thread, 256 threads/block

// ---------------------------------------------------------------------------
// Kernel 1: per-tile activity flags.  flags[n*16 + th*4 + tw] = 1.0 if any
// |x| > THR within the 32x32 spatial tile across all 128 channels.
// Early-exit: dense-random tiles exit after the first chunk (~4KB read).
// ---------------------------------------------------------------------------
__global__ __launch_bounds__(256) void flags_kernel(const float* __restrict__ x,
                                                    float* __restrict__ flags) {
    const int b  = blockIdx.x;          // 0..255 : n*16 + tile
    const int n  = b >> 4;
    const int t  = b & 15;
    const int th = t >> 2;
    const int tw = t & 3;
    const float* base = x + ((size_t)n * CIN * HH * WWID) + (size_t)th * TILE * WWID + tw * TILE;

    __shared__ int found;
    if (threadIdx.x == 0) found = 0;
    __syncthreads();

    int done = 0;
    for (int it = 0; it < 128 && !done; ++it) {
        const int m  = it * 256 + threadIdx.x;
        const int c  = m >> 8;          // channel
        const int r  = (m >> 3) & 31;   // row in tile
        const int cw = m & 7;           // float4 within row
        const float4 v = *(const float4*)(base + (size_t)c * (HH * WWID) + r * WWID + cw * 4);
        if (fabsf(v.x) > THR || fabsf(v.y) > THR || fabsf(v.z) > THR || fabsf(v.w) > THR)
            found = 1;                  // benign race (monotonic 0->1)
        __syncthreads();                // (A) all writes for iter visible
        done = found;                   // uniform read
        __syncthreads();                // (B) reads done before next iter's write
    }
    if (threadIdx.x == 0) flags[b] = done ? 1.0f : 0.0f;
}

// ---------------------------------------------------------------------------
// Kernel 2: weight re-layout [CO][CI][3][3] -> w2[ci][k][co]  (one-off, 576KB)
// ---------------------------------------------------------------------------
__global__ __launch_bounds__(256) void wtrans_kernel(const float* __restrict__ w,
                                                     float* __restrict__ w2) {
    const int f = blockIdx.x * 256 + threadIdx.x;   // f = (ci*9 + k)*128 + co
    if (f < CIN * 9 * COUT) {
        const int co = f & 127;
        const int rk = f >> 7;          // ci*9 + k
        const int ci = rk / 9;
        const int k  = rk - ci * 9;
        w2[f] = w[((size_t)co * CIN + ci) * 9 + k];
    }
}

// ---------------------------------------------------------------------------
// Kernel 3: direct 3x3 conv, pad 1, per-tile input masking.
// Block tile: 32 co x 16 h x 32 w; C_in chunked by 8.
// Lane mapping (conflict-free LDS): wg=tid&7 (w), cog=(tid>>3)&7 (co),
// wave=tid>>6 (h). Within a wave every s_in/s_w ds_read_b128 touches one
// row = 32 consecutive words = all 32 banks exactly once (8-fold broadcast).
// ---------------------------------------------------------------------------
struct alignas(16) SmemT {
    float s_in[CI_BLK][H_BLK + 2][W_BLK + 4];   // [8][18][36]; row stride 144B (16B mult)
    float s_w[CI_BLK][9][CO_BLK];               // [8][9][32]
    float s_flags[16];
};

#define ELT(v4, i) ((i) == 0 ? (v4).x : (i) == 1 ? (v4).y : (i) == 2 ? (v4).z : (v4).w)
// rp: float4[2] covering 8 consecutive floats
#define GETIN(rp, idx) ((idx) < 4 ? ELT((rp)[0], (idx)) : ELT((rp)[1], (idx) - 4))

__global__ __launch_bounds__(256, 3) void conv_kernel(const float* __restrict__ x,
                                                      const float* __restrict__ w2,
                                                      const float* __restrict__ bias,
                                                      const float* __restrict__ flags,
                                                      float* __restrict__ out) {
    __shared__ SmemT sm;
    const int tid  = threadIdx.x;
    const int wblk = blockIdx.x * W_BLK;
    const int hblk = blockIdx.y * H_BLK;
    const int z    = blockIdx.z;
    const int n    = z >> 2;
    const int cob  = (z & 3) * CO_BLK;

    if (tid < 16) sm.s_flags[tid] = flags[n * 16 + tid];

    const int wg   = tid & 7;           // w-group   (varies within wave)
    const int cog  = (tid >> 3) & 7;    // co-group  (varies within wave)
    const int wv   = tid >> 6;          // wave id -> h (uniform within wave)
    const int w0   = wg * 4;
    const int co_t = cog * 4;
    const int h0   = wv * 4;

    float acc[4][4][4];                 // [co][hh][ww]
#pragma unroll
    for (int a = 0; a < 4; ++a)
#pragma unroll
        for (int b = 0; b < 4; ++b)
#pragma unroll
            for (int c = 0; c < 4; ++c) acc[a][b][c] = 0.0f;

    const size_t x_n = (size_t)n * CIN * HH * WWID;

    for (int cib = 0; cib < CIN; cib += CI_BLK) {
        __syncthreads();   // protect previous iteration's LDS reads

        // ---- stage input chunk [8][18][0..34) with halo, bounds + tile mask ----
        for (int f = tid; f < CI_BLK * 18 * 34; f += 256) {
            const int ci  = f / (18 * 34);
            const int rem = f - ci * (18 * 34);
            const int r   = rem / 34;
            const int c   = rem - r * 34;
            const int h_in = hblk + r - 1;
            const int w_in = wblk + c - 1;
            float v = 0.0f;
            if ((unsigned)h_in < (unsigned)HH && (unsigned)w_in < (unsigned)WWID) {
                v = x[x_n + (size_t)(cib + ci) * (HH * WWID) + (size_t)h_in * WWID + w_in]
                    * sm.s_flags[((h_in >> 5) << 2) + (w_in >> 5)];
            }
            sm.s_in[ci][r][c] = v;
        }
        // ---- stage weight chunk: w2[ci][k][cob..cob+31] (sequential LDS writes) ----
        for (int f = tid; f < CI_BLK * 9 * CO_BLK; f += 256) {
            const int ci  = f / (9 * CO_BLK);
            const int rem = f - ci * (9 * CO_BLK);
            const int k   = rem / CO_BLK;
            const int co  = rem - k * CO_BLK;
            ((float*)sm.s_w)[f] = w2[(size_t)(cib + ci) * (9 * COUT) + k * COUT + cob + co];
        }
        __syncthreads();

        // ---- compute: rolling 4-row register window, fully unrolled ----
#pragma unroll 1
        for (int ci = 0; ci < CI_BLK; ++ci) {
            float4 r4[4][2];            // slot s holds LDS row (h0 + rolling), 8 floats
#pragma unroll
            for (int s = 0; s < 4; ++s) {
                r4[s][0] = *(const float4*)&sm.s_in[ci][h0 + s][w0];
                r4[s][1] = *(const float4*)&sm.s_in[ci][h0 + s][w0 + 4];
            }
#pragma unroll
            for (int kh = 0; kh < 3; ++kh) {
                if (kh == 1) {          // overwrite slot 0 with LDS row h0+4
                    r4[0][0] = *(const float4*)&sm.s_in[ci][h0 + 4][w0];
                    r4[0][1] = *(const float4*)&sm.s_in[ci][h0 + 4][w0 + 4];
                } else if (kh == 2) {   // overwrite slot 1 with LDS row h0+5
                    r4[1][0] = *(const float4*)&sm.s_in[ci][h0 + 5][w0];
                    r4[1][1] = *(const float4*)&sm.s_in[ci][h0 + 5][w0 + 4];
                }
                const float4 wf0 = *(const float4*)&sm.s_w[ci][kh * 3 + 0][co_t];
                const float4 wf1 = *(const float4*)&sm.s_w[ci][kh * 3 + 1][co_t];
                const float4 wf2 = *(const float4*)&sm.s_w[ci][kh * 3 + 2][co_t];
#pragma unroll
                for (int hh = 0; hh < 4; ++hh) {
                    const int s = (hh + kh) & 3;   // compile-time after unroll
#pragma unroll
                    for (int ww = 0; ww < 4; ++ww) {
                        const float i0 = GETIN(r4[s], ww + 0);
                        const float i1 = GETIN(r4[s], ww + 1);
                        const float i2 = GETIN(r4[s], ww + 2);
                        acc[0][hh][ww] = fmaf(i0, wf0.x, acc[0][hh][ww]);
                        acc[1][hh][ww] = fmaf(i0, wf0.y, acc[1][hh][ww]);
                        acc[2][hh][ww] = fmaf(i0, wf0.z, acc[2][hh][ww]);
                        acc[3][hh][ww] = fmaf(i0, wf0.w, acc[3][hh][ww]);
                        acc[0][hh][ww] = fmaf(i1, wf1.x, acc[0][hh][ww]);
                        acc[1][hh][ww] = fmaf(i1, wf1.y, acc[1][hh][ww]);
                        acc[2][hh][ww] = fmaf(i1, wf1.z, acc[2][hh][ww]);
                        acc[3][hh][ww] = fmaf(i1, wf1.w, acc[3][hh][ww]);
                        acc[0][hh][ww] = fmaf(i2, wf2.x, acc[0][hh][ww]);
                        acc[1][hh][ww] = fmaf(i2, wf2.y, acc[1][hh][ww]);
                        acc[2][hh][ww] = fmaf(i2, wf2.z, acc[2][hh][ww]);
                        acc[3][hh][ww] = fmaf(i2, wf2.w, acc[3][hh][ww]);
                    }
                }
            }
        }
    }

    // ---- epilogue: +bias, float4 stores ----
    const float4 b4 = *(const float4*)&bias[cob + co_t];
#pragma unroll
    for (int co = 0; co < 4; ++co) {
        const float bb = ELT(b4, co);
#pragma unroll
        for (int hh = 0; hh < 4; ++hh) {
            float4 o;
            o.x = acc[co][hh][0] + bb;
            o.y = acc[co][hh][1] + bb;
            o.z = acc[co][hh][2] + bb;
            o.w = acc[co][hh][3] + bb;
            const size_t off = ((size_t)(n * COUT + cob + co_t + co) * HH + (hblk + h0 + hh)) * WWID
                               + wblk + w0;
            *(float4*)&out[off] = o;
        }
    }
}

// ---------------------------------------------------------------------------
extern "C" void kernel_launch(void* const* d_in, const int* in_sizes, int n_in,
                              void* d_out, int out_size, void* d_ws, size_t ws_size,
                              hipStream_t stream) {
    const float* x    = (const float*)d_in[0];
    const float* w    = (const float*)d_in[1];
    const float* bias = (const float*)d_in[2];
    float* out = (float*)d_out;

    // workspace layout: [0,1024) flags (256 floats), [1024, +576KB) w2
    float* flags = (float*)d_ws;
    float* w2    = (float*)((char*)d_ws + 1024);

    flags_kernel<<<NB * 16, 256, 0, stream>>>(x, flags);
    wtrans_kernel<<<(CIN * 9 * COUT + 255) / 256, 256, 0, stream>>>(w, w2);

    dim3 grid(WWID / W_BLK, HH / H_BLK, NB * (COUT / CO_BLK));   // (4, 8, 64)
    conv_kernel<<<grid, 256, 0, stream>>>(x, w2, bias, flags, out);
}

// Round 3
// 766.909 us; speedup vs baseline: 2.0641x; 1.6201x over previous
//
#include <hip/hip_runtime.h>
#include <hip/hip_bf16.h>
#include <cstddef>

// Problem constants
#define NB     16
#define CIN    128
#define COUT   128
#define HH     128
#define WWID   128
#define THR    1e-6f

typedef __attribute__((ext_vector_type(8))) short bf16x8;   // 8 bf16 (4 VGPRs)
typedef __attribute__((ext_vector_type(4))) float f32x4;    // MFMA accumulator

union U8 { ushort u[8]; bf16x8 v; };

__device__ inline ushort f32_to_bf16_rne(float f) {
    union { float f; unsigned u; } v; v.f = f;
    return (ushort)((v.u + 0x7FFFu + ((v.u >> 16) & 1u)) >> 16);
}
__device__ inline float bf16_to_f32(ushort h) {
    union { unsigned u; float f; } v; v.u = ((unsigned)h) << 16;
    return v.f;
}

// ---------------------------------------------------------------------------
// Kernel 1: per-tile activity flags (unchanged from R2 — passing).
// ---------------------------------------------------------------------------
__global__ __launch_bounds__(256) void flags_kernel(const float* __restrict__ x,
                                                    float* __restrict__ flags) {
    const int b  = blockIdx.x;          // n*16 + tile
    const int n  = b >> 4;
    const int t  = b & 15;
    const int th = t >> 2;
    const int tw = t & 3;
    const float* base = x + ((size_t)n * CIN * HH * WWID) + (size_t)th * 32 * WWID + tw * 32;

    __shared__ int found;
    if (threadIdx.x == 0) found = 0;
    __syncthreads();

    int done = 0;
    for (int it = 0; it < 128 && !done; ++it) {
        const int m  = it * 256 + threadIdx.x;
        const int c  = m >> 8;
        const int r  = (m >> 3) & 31;
        const int cw = m & 7;
        const float4 v = *(const float4*)(base + (size_t)c * (HH * WWID) + r * WWID + cw * 4);
        if (fabsf(v.x) > THR || fabsf(v.y) > THR || fabsf(v.z) > THR || fabsf(v.w) > THR)
            found = 1;                  // benign monotonic race
        __syncthreads();
        done = found;
        __syncthreads();
    }
    if (threadIdx.x == 0) flags[b] = done ? 1.0f : 0.0f;
}

// ---------------------------------------------------------------------------
// Kernel 2: weight split+re-layout  w[co][ci][kh][kw] f32 ->
//   whi/wlo[tap][ci>>3][co][ci&7] bf16  (A-fragment-ready: lane co contiguous)
// ---------------------------------------------------------------------------
__global__ __launch_bounds__(256) void wtrans_kernel(const float* __restrict__ w,
                                                     ushort* __restrict__ whi,
                                                     ushort* __restrict__ wlo) {
    const int f = blockIdx.x * 256 + threadIdx.x;   // 9*16*128*8 = 147456
    if (f < 9 * 16 * 128 * 8) {
        const int j   = f & 7;
        const int co  = (f >> 3) & 127;
        const int t2  = f >> 10;        // tap*16 + cb
        const int cb  = t2 & 15;
        const int tap = t2 >> 4;
        const int ci  = cb * 8 + j;
        const float v = w[((size_t)co * CIN + ci) * 9 + tap];
        const ushort h = f32_to_bf16_rne(v);
        whi[f] = h;
        wlo[f] = f32_to_bf16_rne(v - bf16_to_f32(h));
    }
}

// ---------------------------------------------------------------------------
// Kernel 3: bf16x3-split implicit-GEMM conv via MFMA 16x16x32.
// Block: 128 co x (4h x 32w) spatial. 4 waves = 2(co) x 2(spatial-h).
// Wave: 4 M-tiles (co 16) x 4 N-tiles (16 spatial). K: 4 ci-chunks of 32,
// 9 taps per chunk reusing the staged LDS chunk.
// LDS X layout: [h' 0..5][g 0..3][w' 0..33][8 ci] bf16, hi + lo arrays.
//   B-frag read: lane(c=l&15,g=l>>4) -> 16B at ((h'*4+g)*34+w0+c+kw)*16  (contiguous/quarter-wave)
//   Staging write: item q -> q*16B (fully linear, conflict-free)
// A-frags direct from global whi/wlo (L1-resident, coalesced b128).
// ---------------------------------------------------------------------------
__global__ __launch_bounds__(256, 2) void conv_kernel(const float* __restrict__ x,
                                                      const ushort* __restrict__ whi,
                                                      const ushort* __restrict__ wlo,
                                                      const float* __restrict__ bias,
                                                      const float* __restrict__ flags,
                                                      float* __restrict__ out) {
    __shared__ ushort xhi[6 * 4 * 34 * 8];   // 13056 B
    __shared__ ushort xlo[6 * 4 * 34 * 8];   // 13056 B
    __shared__ float  s_flags[16];

    const int tid  = threadIdx.x;
    const int wblk = blockIdx.x * 32;
    const int hblk = blockIdx.y * 4;
    const int n    = blockIdx.z;

    if (tid < 16) s_flags[tid] = flags[n * 16 + tid];
    __syncthreads();

    const int lane = tid & 63;
    const int wid  = tid >> 6;
    const int c    = lane & 15;          // MFMA col lane
    const int g    = lane >> 4;          // MFMA k-group
    const int cow  = (wid >> 1) * 64;    // wave co base (0 or 64)
    const int wvh  = (wid & 1) * 2;      // wave local-h base (0 or 2)

    f32x4 acc[4][4];
#pragma unroll
    for (int m = 0; m < 4; ++m)
#pragma unroll
        for (int n2 = 0; n2 < 4; ++n2) acc[m][n2] = (f32x4)(0.0f);

    const float* xn = x + (size_t)n * CIN * HH * WWID;

    for (int cb4 = 0; cb4 < 4; ++cb4) {      // ci-chunk of 32
        const int cib = cb4 * 32;

        // ---- stage X chunk: 816 items of 8 ci each ----
#pragma unroll
        for (int it = 0; it < 4; ++it) {
            const int q = tid + it * 256;
            if (q < 816) {
                const int wq   = q % 34;
                const int rest = q / 34;
                const int gq   = rest & 3;
                const int hq   = rest >> 2;          // 0..5
                const int h_in = hblk + hq - 1;
                const int w_in = wblk + wq - 1;
                U8 hs, ls;
                if ((unsigned)h_in < (unsigned)HH && (unsigned)w_in < (unsigned)WWID) {
                    const float fl = s_flags[((h_in >> 5) << 2) + (w_in >> 5)];
                    const float* p = xn + (size_t)(cib + gq * 8) * (HH * WWID)
                                        + (size_t)h_in * WWID + w_in;
#pragma unroll
                    for (int j = 0; j < 8; ++j) {
                        const float v = p[(size_t)j * (HH * WWID)] * fl;
                        const ushort h = f32_to_bf16_rne(v);
                        hs.u[j] = h;
                        ls.u[j] = f32_to_bf16_rne(v - bf16_to_f32(h));
                    }
                } else {
#pragma unroll
                    for (int j = 0; j < 8; ++j) { hs.u[j] = 0; ls.u[j] = 0; }
                }
                *reinterpret_cast<bf16x8*>(&xhi[q * 8]) = hs.v;
                *reinterpret_cast<bf16x8*>(&xlo[q * 8]) = ls.v;
            }
        }
        __syncthreads();

        // ---- compute: 9 taps on this ci-chunk ----
#pragma unroll
        for (int kh = 0; kh < 3; ++kh) {
#pragma unroll
            for (int kw = 0; kw < 3; ++kw) {
                const int tap = kh * 3 + kw;
                bf16x8 ahi[4], alo[4], bhi[4], blo[4];
#pragma unroll
                for (int m = 0; m < 4; ++m) {
                    const int idx = (tap * 16 + cb4 * 4 + g) * 128 + cow + m * 16 + c;
                    ahi[m] = *reinterpret_cast<const bf16x8*>(&whi[(size_t)idx * 8]);
                    alo[m] = *reinterpret_cast<const bf16x8*>(&wlo[(size_t)idx * 8]);
                }
#pragma unroll
                for (int n2 = 0; n2 < 4; ++n2) {
                    const int idx = ((wvh + (n2 >> 1) + kh) * 4 + g) * 34
                                    + (n2 & 1) * 16 + c + kw;
                    bhi[n2] = *reinterpret_cast<const bf16x8*>(&xhi[idx * 8]);
                    blo[n2] = *reinterpret_cast<const bf16x8*>(&xlo[idx * 8]);
                }
                // pass 1: hi*hi  (16 independent MFMAs between dependent ones)
#pragma unroll
                for (int m = 0; m < 4; ++m)
#pragma unroll
                    for (int n2 = 0; n2 < 4; ++n2)
                        acc[m][n2] = __builtin_amdgcn_mfma_f32_16x16x32_bf16(
                            ahi[m], bhi[n2], acc[m][n2], 0, 0, 0);
                // pass 2: hi*lo
#pragma unroll
                for (int m = 0; m < 4; ++m)
#pragma unroll
                    for (int n2 = 0; n2 < 4; ++n2)
                        acc[m][n2] = __builtin_amdgcn_mfma_f32_16x16x32_bf16(
                            ahi[m], blo[n2], acc[m][n2], 0, 0, 0);
                // pass 3: lo*hi
#pragma unroll
                for (int m = 0; m < 4; ++m)
#pragma unroll
                    for (int n2 = 0; n2 < 4; ++n2)
                        acc[m][n2] = __builtin_amdgcn_mfma_f32_16x16x32_bf16(
                            alo[m], bhi[n2], acc[m][n2], 0, 0, 0);
            }
        }
        __syncthreads();   // protect LDS before next chunk's staging
    }

    // ---- epilogue: +bias, store (D: row=co=(g*4+r), col=spatial=c) ----
#pragma unroll
    for (int m = 0; m < 4; ++m) {
        const int co0 = cow + m * 16 + g * 4;
        const float4 b4 = *(const float4*)&bias[co0];
#pragma unroll
        for (int n2 = 0; n2 < 4; ++n2) {
            const int h = hblk + wvh + (n2 >> 1);
            const int w = wblk + (n2 & 1) * 16 + c;
#pragma unroll
            for (int r = 0; r < 4; ++r) {
                const float bb = (r == 0 ? b4.x : r == 1 ? b4.y : r == 2 ? b4.z : b4.w);
                out[(((size_t)(n * COUT + co0 + r)) * HH + h) * WWID + w] =
                    acc[m][n2][r] + bb;
            }
        }
    }
}

// ---------------------------------------------------------------------------
extern "C" void kernel_launch(void* const* d_in, const int* in_sizes, int n_in,
                              void* d_out, int out_size, void* d_ws, size_t ws_size,
                              hipStream_t stream) {
    const float* x    = (const float*)d_in[0];
    const float* w    = (const float*)d_in[1];
    const float* bias = (const float*)d_in[2];
    float* out = (float*)d_out;

    // ws: [0,1024) flags | [1024, +294912) whi | [+294912) wlo   (total 590848 B)
    float*  flags = (float*)d_ws;
    ushort* whi   = (ushort*)((char*)d_ws + 1024);
    ushort* wlo   = (ushort*)((char*)d_ws + 1024 + 9 * 16 * 128 * 8 * 2);

    flags_kernel<<<NB * 16, 256, 0, stream>>>(x, flags);
    wtrans_kernel<<<(9 * 16 * 128 * 8 + 255) / 256, 256, 0, stream>>>(w, whi, wlo);

    dim3 grid(WWID / 32, HH / 4, NB);   // (4, 32, 16) = 2048 blocks
    conv_kernel<<<grid, 256, 0, stream>>>(x, whi, wlo, bias, flags, out);
}

// Round 6
// 586.262 us; speedup vs baseline: 2.7001x; 1.3081x over previous
//
#include <hip/hip_runtime.h>
#include <hip/hip_bf16.h>
#include <cstddef>

// Problem constants
#define NB     16
#define CIN    128
#define COUT   128
#define HH     128
#define WWID   128
#define THR    1e-6f

typedef __attribute__((ext_vector_type(8))) short bf16x8;   // 8 bf16 (4 VGPRs)
typedef __attribute__((ext_vector_type(4))) float f32x4;    // MFMA accumulator

union U8 { ushort u[8]; bf16x8 v; };

__device__ inline ushort f32_to_bf16_rne(float f) {
    union { float f; unsigned u; } v; v.f = f;
    return (ushort)((v.u + 0x7FFFu + ((v.u >> 16) & 1u)) >> 16);
}
__device__ inline float bf16_to_f32(ushort h) {
    union { unsigned u; float f; } v; v.u = ((unsigned)h) << 16;
    return v.f;
}

// ---------------------------------------------------------------------------
// Kernel 1: per-tile activity flags (unchanged — validated).
// ---------------------------------------------------------------------------
__global__ __launch_bounds__(256) void flags_kernel(const float* __restrict__ x,
                                                    float* __restrict__ flags) {
    const int b  = blockIdx.x;          // n*16 + tile
    const int n  = b >> 4;
    const int t  = b & 15;
    const int th = t >> 2;
    const int tw = t & 3;
    const float* base = x + ((size_t)n * CIN * HH * WWID) + (size_t)th * 32 * WWID + tw * 32;

    __shared__ int found;
    if (threadIdx.x == 0) found = 0;
    __syncthreads();

    int done = 0;
    for (int it = 0; it < 128 && !done; ++it) {
        const int m  = it * 256 + threadIdx.x;
        const int c  = m >> 8;
        const int r  = (m >> 3) & 31;
        const int cw = m & 7;
        const float4 v = *(const float4*)(base + (size_t)c * (HH * WWID) + r * WWID + cw * 4);
        if (fabsf(v.x) > THR || fabsf(v.y) > THR || fabsf(v.z) > THR || fabsf(v.w) > THR)
            found = 1;                  // benign monotonic race
        __syncthreads();
        done = found;
        __syncthreads();
    }
    if (threadIdx.x == 0) flags[b] = done ? 1.0f : 0.0f;
}

// ---------------------------------------------------------------------------
// Kernel 2: weight split+re-layout  w[co][ci][kh][kw] f32 ->
//   whi/wlo[tap][ci>>3][co][ci&7] bf16  (A-fragment-ready; validated R3)
// ---------------------------------------------------------------------------
__global__ __launch_bounds__(256) void wtrans_kernel(const float* __restrict__ w,
                                                     ushort* __restrict__ whi,
                                                     ushort* __restrict__ wlo) {
    const int f = blockIdx.x * 256 + threadIdx.x;   // 9*16*128*8 = 147456
    if (f < 9 * 16 * 128 * 8) {
        const int j   = f & 7;
        const int co  = (f >> 3) & 127;
        const int t2  = f >> 10;        // tap*16 + cb
        const int cb  = t2 & 15;
        const int tap = t2 >> 4;
        const int ci  = cb * 8 + j;
        const float v = w[((size_t)co * CIN + ci) * 9 + tap];
        const ushort h = f32_to_bf16_rne(v);
        whi[f] = h;
        wlo[f] = f32_to_bf16_rne(v - bf16_to_f32(h));
    }
}

// ---------------------------------------------------------------------------
// Kernel 3: bf16x3-split implicit-GEMM conv via MFMA 16x16x32.
// 512 threads = 8 waves = 4 co-groups x 2 h-groups. Block tile: 128co x 4h x 32w.
// Wave tile: 32co (2 M-tiles) x 64 spatial (4 N-tiles).  acc 32 + Bfrag 32 +
// Afrag 16 regs -> total <=128 -> 4 waves/SIMD (16 waves/CU).
// K-loop: 4 ci-chunks of 32; 9 taps reuse the staged LDS x chunk.
// Epilogue: per-wave LDS bounce -> full-128B-line dwordx4 stores.
// ---------------------------------------------------------------------------
union SmemU {
    struct { ushort hi[6 * 4 * 34 * 8]; ushort lo[6 * 4 * 34 * 8]; } x;  // 52224 B
    float ep[8][2][16][68];                                              // 69632 B
};

__global__ __launch_bounds__(512, 4) void conv_kernel(const float* __restrict__ x,
                                                      const ushort* __restrict__ whi,
                                                      const ushort* __restrict__ wlo,
                                                      const float* __restrict__ bias,
                                                      const float* __restrict__ flags,
                                                      float* __restrict__ out) {
    __shared__ SmemU sm;
    __shared__ float s_flags[16];

    const int tid  = threadIdx.x;
    const int wblk = blockIdx.x * 32;
    const int hblk = blockIdx.y * 4;
    const int n    = blockIdx.z;

    if (tid < 16) s_flags[tid] = flags[n * 16 + tid];
    __syncthreads();

    const int lane = tid & 63;
    const int wid  = tid >> 6;           // 0..7
    const int c    = lane & 15;          // MFMA col lane
    const int g    = lane >> 4;          // MFMA k-group
    const int cow  = (wid >> 1) * 32;    // wave co base: 0,32,64,96
    const int spg  = wid & 1;            // wave h-group: local h = spg*2 + 0..1

    f32x4 acc[2][4];
#pragma unroll
    for (int m = 0; m < 2; ++m)
#pragma unroll
        for (int n2 = 0; n2 < 4; ++n2) acc[m][n2] = (f32x4)(0.0f);

    const float* xn = x + (size_t)n * CIN * HH * WWID;

    for (int cb4 = 0; cb4 < 4; ++cb4) {      // ci-chunk of 32
        const int cib = cb4 * 32;
        __syncthreads();   // previous chunk's LDS reads done

        // ---- stage x chunk: 816 items ([6 rows][4 g][34 w] of 8 ci) ----
#pragma unroll
        for (int it = 0; it < 2; ++it) {
            const int q = tid + it * 512;
            if (q < 816) {
                const int wq   = q % 34;
                const int rest = q / 34;
                const int gq   = rest & 3;
                const int hq   = rest >> 2;          // 0..5
                const int h_in = hblk + hq - 1;
                const int w_in = wblk + wq - 1;
                U8 hs, ls;
                if ((unsigned)h_in < (unsigned)HH && (unsigned)w_in < (unsigned)WWID) {
                    const float fl = s_flags[((h_in >> 5) << 2) + (w_in >> 5)];
                    const float* p = xn + (size_t)(cib + gq * 8) * (HH * WWID)
                                        + (size_t)h_in * WWID + w_in;
#pragma unroll
                    for (int j = 0; j < 8; ++j) {
                        const float v = p[(size_t)j * (HH * WWID)] * fl;
                        const ushort h = f32_to_bf16_rne(v);
                        hs.u[j] = h;
                        ls.u[j] = f32_to_bf16_rne(v - bf16_to_f32(h));
                    }
                } else {
#pragma unroll
                    for (int j = 0; j < 8; ++j) { hs.u[j] = 0; ls.u[j] = 0; }
                }
                *reinterpret_cast<bf16x8*>(&sm.x.hi[q * 8]) = hs.v;
                *reinterpret_cast<bf16x8*>(&sm.x.lo[q * 8]) = ls.v;
            }
        }
        __syncthreads();

        // ---- compute: 9 taps on this ci-chunk ----
#pragma unroll
        for (int kh = 0; kh < 3; ++kh) {
#pragma unroll
            for (int kw = 0; kw < 3; ++kw) {
                const int tap = kh * 3 + kw;
                bf16x8 bhi[4], blo[4];
#pragma unroll
                for (int n2 = 0; n2 < 4; ++n2) {
                    const int idx = (((spg * 2 + (n2 >> 1) + kh) * 4 + g) * 34
                                     + (n2 & 1) * 16 + c + kw) * 8;
                    bhi[n2] = *reinterpret_cast<const bf16x8*>(&sm.x.hi[idx]);
                    blo[n2] = *reinterpret_cast<const bf16x8*>(&sm.x.lo[idx]);
                }
                bf16x8 ahi[2], alo[2];
#pragma unroll
                for (int m = 0; m < 2; ++m) {
                    const int idx = ((tap * 16 + cb4 * 4 + g) * 128 + cow + m * 16 + c) * 8;
                    ahi[m] = *reinterpret_cast<const bf16x8*>(&whi[idx]);
                    alo[m] = *reinterpret_cast<const bf16x8*>(&wlo[idx]);
                }
                // pass 1: hi*hi
#pragma unroll
                for (int m = 0; m < 2; ++m)
#pragma unroll
                    for (int n2 = 0; n2 < 4; ++n2)
                        acc[m][n2] = __builtin_amdgcn_mfma_f32_16x16x32_bf16(
                            ahi[m], bhi[n2], acc[m][n2], 0, 0, 0);
                // pass 2: hi*lo
#pragma unroll
                for (int m = 0; m < 2; ++m)
#pragma unroll
                    for (int n2 = 0; n2 < 4; ++n2)
                        acc[m][n2] = __builtin_amdgcn_mfma_f32_16x16x32_bf16(
                            ahi[m], blo[n2], acc[m][n2], 0, 0, 0);
                // pass 3: lo*hi
#pragma unroll
                for (int m = 0; m < 2; ++m)
#pragma unroll
                    for (int n2 = 0; n2 < 4; ++n2)
                        acc[m][n2] = __builtin_amdgcn_mfma_f32_16x16x32_bf16(
                            alo[m], bhi[n2], acc[m][n2], 0, 0, 0);
            }
        }
    }

    // ---- epilogue: +bias, LDS transpose bounce, full-line dwordx4 stores ----
    __syncthreads();   // all waves done reading x LDS before aliasing with ep

#pragma unroll
    for (int m = 0; m < 2; ++m) {
        const int co0 = cow + m * 16;
        const float4 b4 = *(const float4*)&bias[co0 + g * 4];
#pragma unroll
        for (int n2 = 0; n2 < 4; ++n2) {
#pragma unroll
            for (int r = 0; r < 4; ++r) {
                const float bb = (r == 0 ? b4.x : r == 1 ? b4.y : r == 2 ? b4.z : b4.w);
                // D mapping: row(co)=g*4+r, col(spatial)=n2*16+c ; s = h*32+w
                sm.ep[wid][m][g * 4 + r][n2 * 16 + c] = acc[m][n2][r] + bb;
            }
        }
    }
    // wave-local LDS: per-wave region, in-order DS pipe; compiler inserts lgkmcnt
#pragma unroll
    for (int m = 0; m < 2; ++m) {
        const int co0 = cow + m * 16;
#pragma unroll
        for (int half = 0; half < 2; ++half) {
#pragma unroll
            for (int rr = 0; rr < 2; ++rr) {
                const int row = rr * 8 + (lane >> 3);
                const float4 v = *(const float4*)&sm.ep[wid][m][row][half * 32 + (lane & 7) * 4];
                const int h = hblk + spg * 2 + half;
                const int w = wblk + (lane & 7) * 4;
                *(float4*)&out[(((size_t)(n * COUT + co0 + row)) * HH + h) * WWID + w] = v;
            }
        }
    }
}

// ---------------------------------------------------------------------------
extern "C" void kernel_launch(void* const* d_in, const int* in_sizes, int n_in,
                              void* d_out, int out_size, void* d_ws, size_t ws_size,
                              hipStream_t stream) {
    const float* x    = (const float*)d_in[0];
    const float* w    = (const float*)d_in[1];
    const float* bias = (const float*)d_in[2];
    float* out = (float*)d_out;

    // ws: [0,1024) flags | [1024, +294912) whi | [+294912) wlo
    float*  flags = (float*)d_ws;
    ushort* whi   = (ushort*)((char*)d_ws + 1024);
    ushort* wlo   = (ushort*)((char*)d_ws + 1024 + 9 * 16 * 128 * 8 * 2);

    flags_kernel<<<NB * 16, 256, 0, stream>>>(x, flags);
    wtrans_kernel<<<(9 * 16 * 128 * 8 + 255) / 256, 256, 0, stream>>>(w, whi, wlo);

    dim3 grid(WWID / 32, HH / 4, NB);   // (4, 32, 16) = 2048 blocks
    conv_kernel<<<grid, 512, 0, stream>>>(x, whi, wlo, bias, flags, out);
}